// Round 1
// baseline (161.998 us; speedup 1.0000x reference)
//
#include <hip/hip_runtime.h>

typedef __attribute__((ext_vector_type(8))) short bf16x8;
typedef __attribute__((ext_vector_type(4))) float f32x4;

#define WIDTH  2048
#define NHEADS 16
#define HDIM   128
#define BM     64

__device__ __forceinline__ unsigned short f2bf(float f) {
  union { float f; unsigned int u; } v; v.f = f;
  unsigned int u = v.u;
  unsigned int r = (u + 0x7FFFu + ((u >> 16) & 1u)) >> 16;  // RNE
  return (unsigned short)r;
}

// Prep: transpose w_in/w_a [h][i][j] -> bf16 [h][j][i]; precompute 8*softplus(a_param).
__global__ __launch_bounds__(256) void prep_kernel(
    const float* __restrict__ w_in, const float* __restrict__ w_a,
    const float* __restrict__ a_param,
    unsigned short* __restrict__ wTin, unsigned short* __restrict__ wTa,
    float* __restrict__ sp8) {
  int tid = blockIdx.x * 256 + threadIdx.x;    // 0 .. 16*128*128-1
  int h   = tid >> 14;
  int rem = tid & 16383;
  int j   = rem >> 7;
  int i   = rem & 127;
  int src = (h << 14) + (i << 7) + j;
  wTin[tid] = f2bf(w_in[src]);
  wTa[tid]  = f2bf(w_a[src]);
  if (tid < WIDTH) {
    float v  = a_param[tid];
    float sp = (v > 20.0f) ? v : log1pf(__expf(v));
    sp8[tid] = 8.0f * sp;
  }
}

// Main: block = 64 rows x 1 head. 4 waves x (16 rows-frag x 32 cols each... )
// wave w owns output cols [w*32, w*32+32), all 64 rows (M_rep=4, N_rep=2).
__global__ __launch_bounds__(256) void rglru_kernel(
    const float* __restrict__ x, const float* __restrict__ state,
    const float* __restrict__ b_in, const float* __restrict__ b_a,
    const unsigned short* __restrict__ wTin, const unsigned short* __restrict__ wTa,
    const float* __restrict__ sp8, float* __restrict__ out) {
  __shared__ unsigned short xs[BM * HDIM];  // bf16 x-tile, XOR-swizzled

  const int bid  = blockIdx.x;
  const int h    = bid & (NHEADS - 1);
  const int rb   = bid >> 4;
  const int t    = threadIdx.x;
  const int lane = t & 63;
  const int wid  = t >> 6;
  const int l15  = lane & 15;
  const int l4   = lane >> 4;

  // ---- stage x tile (BM x HDIM f32 -> bf16 LDS, swizzled) ----
  const float* xtile = x + (long)rb * BM * WIDTH + h * HDIM;
#pragma unroll
  for (int it = 0; it < 8; ++it) {
    int idx = it * 256 + t;            // float4 index within tile (0..2047)
    int r   = idx >> 5;                // row 0..63
    int c4  = idx & 31;                // float4 within row
    float4 v = *(reinterpret_cast<const float4*>(xtile + (long)r * WIDTH) + c4);
    uint2 p;
    p.x = (unsigned int)f2bf(v.x) | ((unsigned int)f2bf(v.y) << 16);
    p.y = (unsigned int)f2bf(v.z) | ((unsigned int)f2bf(v.w) << 16);
    int off = (r * 256 + c4 * 8) ^ ((r & 7) << 4);
    *reinterpret_cast<uint2*>(reinterpret_cast<char*>(xs) + off) = p;
  }
  __syncthreads();

  // ---- MFMA: y_in = x @ w_in, y_a = x @ w_a (per head) ----
  f32x4 acc_in[4][2], acc_a[4][2];
#pragma unroll
  for (int m = 0; m < 4; ++m)
#pragma unroll
    for (int n = 0; n < 2; ++n) {
      acc_in[m][n] = (f32x4)(0.0f);
      acc_a[m][n]  = (f32x4)(0.0f);
    }

  const unsigned short* wbin = wTin + ((h * HDIM + wid * 32) * HDIM);
  const unsigned short* wba  = wTa  + ((h * HDIM + wid * 32) * HDIM);

#pragma unroll
  for (int kk = 0; kk < 4; ++kk) {
    bf16x8 afr[4];
#pragma unroll
    for (int m = 0; m < 4; ++m) {
      int row  = m * 16 + l15;
      int boff = (row * 256 + kk * 64 + l4 * 16) ^ ((row & 7) << 4);
      afr[m] = *reinterpret_cast<const bf16x8*>(
          reinterpret_cast<const char*>(xs) + boff);
    }
    bf16x8 bin[2], ba[2];
#pragma unroll
    for (int n = 0; n < 2; ++n) {
      int widx = (n * 16 + l15) * HDIM + kk * 32 + l4 * 8;
      bin[n] = *reinterpret_cast<const bf16x8*>(wbin + widx);
      ba[n]  = *reinterpret_cast<const bf16x8*>(wba + widx);
    }
#pragma unroll
    for (int m = 0; m < 4; ++m)
#pragma unroll
      for (int n = 0; n < 2; ++n) {
        acc_in[m][n] = __builtin_amdgcn_mfma_f32_16x16x32_bf16(
            afr[m], bin[n], acc_in[m][n], 0, 0, 0);
        acc_a[m][n] = __builtin_amdgcn_mfma_f32_16x16x32_bf16(
            afr[m], ba[n], acc_a[m][n], 0, 0, 0);
      }
  }

  // ---- epilogue: gates + elementwise combine ----
  // C/D layout (16x16x32): col = lane&15, row = (lane>>4)*4 + reg
#pragma unroll
  for (int n = 0; n < 2; ++n) {
    int colh = wid * 32 + n * 16 + l15;         // col within head [0,128)
    int col  = h * HDIM + colh;                 // col within width
    float sp  = sp8[col];
    float bi  = b_in[h * HDIM + colh];
    float bav = b_a[h * HDIM + colh];
#pragma unroll
    for (int m = 0; m < 4; ++m) {
      int row0 = rb * BM + m * 16 + l4 * 4;
#pragma unroll
      for (int r = 0; r < 4; ++r) {
        long off = (long)(row0 + r) * WIDTH + col;
        float yin = acc_in[m][n][r] + bi;
        float ya  = acc_a[m][n][r] + bav;
        float gx = __builtin_amdgcn_rcpf(1.0f + __expf(-yin));
        float ga = __builtin_amdgcn_rcpf(1.0f + __expf(-ya));
        float av = __expf(-ga * sp);
        float sc = sqrtf(fmaxf(1.0f - av * av, 0.0f));
        out[off] = av * state[off] + gx * x[off] * sc;
      }
    }
  }
}

extern "C" void kernel_launch(void* const* d_in, const int* in_sizes, int n_in,
                              void* d_out, int out_size, void* d_ws, size_t ws_size,
                              hipStream_t stream) {
  const float* x       = (const float*)d_in[0];
  const float* state   = (const float*)d_in[1];
  const float* w_in    = (const float*)d_in[2];
  const float* b_in    = (const float*)d_in[3];
  const float* w_a     = (const float*)d_in[4];
  const float* b_a     = (const float*)d_in[5];
  const float* a_param = (const float*)d_in[6];
  float* out = (float*)d_out;

  unsigned short* wTin = (unsigned short*)d_ws;
  unsigned short* wTa  = wTin + NHEADS * HDIM * HDIM;
  float*          sp8  = (float*)(wTa + NHEADS * HDIM * HDIM);

  // prep: 16*128*128 = 262144 elements -> 1024 blocks
  hipLaunchKernelGGL(prep_kernel, dim3(1024), dim3(256), 0, stream,
                     w_in, w_a, a_param, wTin, wTa, sp8);

  // main: (16384/64) row-blocks * 16 heads = 4096 blocks
  hipLaunchKernelGGL(rglru_kernel, dim3(4096), dim3(256), 0, stream,
                     x, state, b_in, b_a, wTin, wTa, sp8, out);
}